// Round 1
// baseline (159.997 us; speedup 1.0000x reference)
//
#include <hip/hip_runtime.h>

// Problem constants (match reference)
#define DEPTH    257     // 256 train ids + OOV
#define OUT_DIM  64
#define OOV_B    256
#define LUT_SIZE 512

// Prologue: transpose W [OUT_DIM][DEPTH] -> WT [DEPTH][OUT_DIM] in workspace.
// 16,448 elements, one-shot, negligible cost; makes each gathered row a
// contiguous 256B read.
__global__ void transpose_W_kernel(const float* __restrict__ W,
                                   float* __restrict__ WT) {
    int idx = blockIdx.x * blockDim.x + threadIdx.x;
    int total = OUT_DIM * DEPTH;
    if (idx < total) {
        int o = idx / DEPTH;           // output-dim index (row of W)
        int b = idx - o * DEPTH;       // bucket index (col of W)
        WT[b * OUT_DIM + o] = W[idx];  // coalesced read, scattered (tiny) write
    }
}

// Main: each thread produces one float4 of the [N][64] output.
// j = row*16 + q ; store coalesced dwordx4; WT row read is 4 contiguous
// 256B segments per wave (L2-resident).
__global__ void gather_rows_kernel(const float* __restrict__ raw_ids,
                                   const float4* __restrict__ WT4,
                                   const int* __restrict__ lut,
                                   float4* __restrict__ out4,
                                   int total_quads) {
    int stride = gridDim.x * blockDim.x;
    for (int j = blockIdx.x * blockDim.x + threadIdx.x; j < total_quads;
         j += stride) {
        int row = j >> 4;          // output row
        int q   = j & 15;          // which float4 of the 64-float row
        int id  = __float2int_rn(raw_ids[row]);   // round-nearest-even, exact here
        int bucket = ((unsigned)id < LUT_SIZE) ? lut[id] : OOV_B;
        out4[j] = WT4[bucket * (OUT_DIM / 4) + q];
    }
}

// Fallback (only if ws_size is somehow too small): gather directly from W
// with 4 strided scalar loads per float4. Correct but slower.
__global__ void gather_rows_direct_kernel(const float* __restrict__ raw_ids,
                                          const float* __restrict__ W,
                                          const int* __restrict__ lut,
                                          float4* __restrict__ out4,
                                          int total_quads) {
    int stride = gridDim.x * blockDim.x;
    for (int j = blockIdx.x * blockDim.x + threadIdx.x; j < total_quads;
         j += stride) {
        int row = j >> 4;
        int q   = j & 15;
        int id  = __float2int_rn(raw_ids[row]);
        int bucket = ((unsigned)id < LUT_SIZE) ? lut[id] : OOV_B;
        float4 v;
        v.x = W[(4 * q + 0) * DEPTH + bucket];
        v.y = W[(4 * q + 1) * DEPTH + bucket];
        v.z = W[(4 * q + 2) * DEPTH + bucket];
        v.w = W[(4 * q + 3) * DEPTH + bucket];
        out4[j] = v;
    }
}

extern "C" void kernel_launch(void* const* d_in, const int* in_sizes, int n_in,
                              void* d_out, int out_size, void* d_ws,
                              size_t ws_size, hipStream_t stream) {
    const float* raw_ids = (const float*)d_in[0];   // [N] f32 (integral values)
    const float* W       = (const float*)d_in[1];   // [64][257] f32
    const int*   lut     = (const int*)d_in[2];     // [512] i32
    float*       out     = (float*)d_out;           // [N][64] f32

    const int n = in_sizes[0];                      // 2,097,152
    const int total_quads = n * (OUT_DIM / 4);      // 33,554,432 (fits int)

    const int BLOCK = 256;
    const int GRID  = 2048;                         // grid-stride, 64 iters/thread

    const size_t wt_bytes = (size_t)DEPTH * OUT_DIM * sizeof(float);
    if (ws_size >= wt_bytes) {
        float* WT = (float*)d_ws;
        const int ttotal = OUT_DIM * DEPTH;
        transpose_W_kernel<<<(ttotal + 1023) / 1024, 1024, 0, stream>>>(W, WT);
        gather_rows_kernel<<<GRID, BLOCK, 0, stream>>>(
            raw_ids, (const float4*)WT, lut, (float4*)out, total_quads);
    } else {
        gather_rows_direct_kernel<<<GRID, BLOCK, 0, stream>>>(
            raw_ids, W, lut, (float4*)out, total_quads);
    }
}

// Round 2
// 109.670 us; speedup vs baseline: 1.4589x; 1.4589x over previous
//
#include <hip/hip_runtime.h>

// Problem constants (match reference)
#define DEPTH    257     // 256 train ids + OOV
#define OUT_DIM  64
#define OOV_B    256
#define LUT_SIZE 512
#define FT_ROWS  513     // rows 0..511 = lut-mapped ids, row 512 = OOV catch-all
#define FT_QUADS (FT_ROWS * (OUT_DIM / 4))   // 8208 float4 = 131,328 B
#define BLOCK    1024
#define GRID     256     // 1 block/CU (131 KB LDS), 16 waves/CU

typedef float f32x4 __attribute__((ext_vector_type(4)));

// Prologue: fused table FT[id][o] = W[o][bucket(id)] for every possible raw
// id in [0,512], row 512 = OOV. Removes the lut indirection from the hot
// loop. 32,832 elements — negligible.
__global__ void build_FT_kernel(const float* __restrict__ W,
                                const int* __restrict__ lut,
                                float* __restrict__ FT) {
    int idx = blockIdx.x * blockDim.x + threadIdx.x;
    if (idx >= FT_ROWS * OUT_DIM) return;
    int r = idx >> 6;                       // raw id (table row)
    int o = idx & 63;                       // output dim
    int bucket = (r < LUT_SIZE) ? lut[r] : OOV_B;
    FT[idx] = W[o * DEPTH + bucket];
}

// Main: FT staged in LDS (131 KB); each thread emits one float4 per step.
// Chain per step: global raw_ids load -> LDS read -> nt store.
__global__ __launch_bounds__(BLOCK) void gather_lds_kernel(
        const float* __restrict__ raw_ids,
        const f32x4* __restrict__ FT4,
        f32x4* __restrict__ out4,
        int total_quads) {
    __shared__ f32x4 sFT[FT_QUADS];        // 131,328 B LDS
    for (int k = threadIdx.x; k < FT_QUADS; k += BLOCK) sFT[k] = FT4[k];
    __syncthreads();

    const int stride = GRID * BLOCK;       // 262,144 quads = 4 MB/step
    int j = blockIdx.x * BLOCK + threadIdx.x;

    // x4 unrolled: batch 4 independent id loads, then 4 LDS reads, 4 stores.
    for (; j + 3 * stride < total_quads; j += 4 * stride) {
        int j0 = j, j1 = j + stride, j2 = j + 2 * stride, j3 = j + 3 * stride;
        float f0 = raw_ids[j0 >> 4];
        float f1 = raw_ids[j1 >> 4];
        float f2 = raw_ids[j2 >> 4];
        float f3 = raw_ids[j3 >> 4];
        unsigned i0 = min((unsigned)__float2int_rn(f0), (unsigned)LUT_SIZE);
        unsigned i1 = min((unsigned)__float2int_rn(f1), (unsigned)LUT_SIZE);
        unsigned i2 = min((unsigned)__float2int_rn(f2), (unsigned)LUT_SIZE);
        unsigned i3 = min((unsigned)__float2int_rn(f3), (unsigned)LUT_SIZE);
        f32x4 v0 = sFT[i0 * 16 + (j0 & 15)];
        f32x4 v1 = sFT[i1 * 16 + (j1 & 15)];
        f32x4 v2 = sFT[i2 * 16 + (j2 & 15)];
        f32x4 v3 = sFT[i3 * 16 + (j3 & 15)];
        __builtin_nontemporal_store(v0, &out4[j0]);
        __builtin_nontemporal_store(v1, &out4[j1]);
        __builtin_nontemporal_store(v2, &out4[j2]);
        __builtin_nontemporal_store(v3, &out4[j3]);
    }
    for (; j < total_quads; j += stride) {
        int id = __float2int_rn(raw_ids[j >> 4]);
        unsigned idx = min((unsigned)id, (unsigned)LUT_SIZE);
        __builtin_nontemporal_store(sFT[idx * 16 + (j & 15)], &out4[j]);
    }
}

// Fallback if ws is too small for FT: direct strided gather from W (correct,
// slower). Same as round-0 fallback.
__global__ void gather_rows_direct_kernel(const float* __restrict__ raw_ids,
                                          const float* __restrict__ W,
                                          const int* __restrict__ lut,
                                          float4* __restrict__ out4,
                                          int total_quads) {
    int stride = gridDim.x * blockDim.x;
    for (int j = blockIdx.x * blockDim.x + threadIdx.x; j < total_quads;
         j += stride) {
        int row = j >> 4;
        int q   = j & 15;
        int id  = __float2int_rn(raw_ids[row]);
        int bucket = ((unsigned)id < LUT_SIZE) ? lut[id] : OOV_B;
        float4 v;
        v.x = W[(4 * q + 0) * DEPTH + bucket];
        v.y = W[(4 * q + 1) * DEPTH + bucket];
        v.z = W[(4 * q + 2) * DEPTH + bucket];
        v.w = W[(4 * q + 3) * DEPTH + bucket];
        out4[j] = v;
    }
}

extern "C" void kernel_launch(void* const* d_in, const int* in_sizes, int n_in,
                              void* d_out, int out_size, void* d_ws,
                              size_t ws_size, hipStream_t stream) {
    const float* raw_ids = (const float*)d_in[0];   // [N] f32 (integral values)
    const float* W       = (const float*)d_in[1];   // [64][257] f32
    const int*   lut     = (const int*)d_in[2];     // [512] i32
    float*       out     = (float*)d_out;           // [N][64] f32

    const int n = in_sizes[0];                      // 2,097,152
    const int total_quads = n * (OUT_DIM / 4);      // 33,554,432

    const size_t ft_bytes = (size_t)FT_ROWS * OUT_DIM * sizeof(float);
    if (ws_size >= ft_bytes) {
        float* FT = (float*)d_ws;
        const int ttotal = FT_ROWS * OUT_DIM;       // 32,832
        build_FT_kernel<<<(ttotal + 255) / 256, 256, 0, stream>>>(W, lut, FT);
        gather_lds_kernel<<<GRID, BLOCK, 0, stream>>>(
            raw_ids, (const f32x4*)FT, (f32x4*)out, total_quads);
    } else {
        gather_rows_direct_kernel<<<2048, 256, 0, stream>>>(
            raw_ids, W, lut, (float4*)out, total_quads);
    }
}